// Round 4
// baseline (411.803 us; speedup 1.0000x reference)
//
#include <hip/hip_runtime.h>

#define NTOKEN 200000
#define NINP   64
#define NEDGE  2000000
#define NBL    12800
#define NBKT   512
#define NPB    391            // nodes per bucket
#define CHUNK  4096
#define NCHUNK ((NEDGE + CHUNK - 1) / CHUNK)   // 489
#define CAP    6144

// ---- inclusive scan of s[0..511] with 256 threads; p is 256-int temp ----
__device__ __forceinline__ void scan512(int* s, int* p) {
    int t = threadIdx.x;
    int a = s[2 * t], b = s[2 * t + 1];
    p[t] = a + b;
    __syncthreads();
    for (int d = 1; d < 256; d <<= 1) {
        int v = (t >= d) ? p[t - d] : 0;
        __syncthreads();
        p[t] += v;
        __syncthreads();
    }
    int incl = p[t];
    s[2 * t + 1] = incl;
    s[2 * t]     = incl - b;
    __syncthreads();
}

__global__ void k_init(int* __restrict__ bCnt, int* __restrict__ flag,
                       int* __restrict__ ncnt) {
    int i = blockIdx.x * blockDim.x + threadIdx.x;
    if (i < NBKT) bCnt[i] = 0;
    if (i < NTOKEN) flag[i] = 0;
    if (i == 0) *ncnt = 0;
}

// ---- pass A: bucket histogram, LDS pre-aggregated ----
__global__ void k_hist(const int* __restrict__ dst, int* __restrict__ bCnt) {
    __shared__ int h[NBKT];
    int t = threadIdx.x;
    h[t] = 0; h[t + 256] = 0;
    __syncthreads();
    for (int e = blockIdx.x * blockDim.x + t; e < NEDGE; e += gridDim.x * blockDim.x)
        atomicAdd(&h[(unsigned)dst[e] / NPB], 1);
    __syncthreads();
    if (h[t])       atomicAdd(&bCnt[t], h[t]);
    if (h[t + 256]) atomicAdd(&bCnt[t + 256], h[t + 256]);
}

// ---- pass S: scan bucket counts ----
__global__ void k_scanB(const int* __restrict__ bCnt, int* __restrict__ bStart,
                        int* __restrict__ gCur) {
    __shared__ int buf[NBKT];
    int t = threadIdx.x;
    int v = bCnt[t];
    buf[t] = v;
    __syncthreads();
    for (int d = 1; d < NBKT; d <<= 1) {
        int add = (t >= d) ? buf[t - d] : 0;
        __syncthreads();
        buf[t] += add;
        __syncthreads();
    }
    bStart[t + 1] = buf[t];
    gCur[t] = buf[t] - v;
    if (t == 0) bStart[0] = 0;
}

// ---- pass B: chunked bucket scatter with coalesced writes ----
__global__ void k_bucket(const int* __restrict__ src, const int* __restrict__ dst,
                         int* __restrict__ gCur, int* __restrict__ E) {
    __shared__ int sv[CHUNK];
    __shared__ int gd[CHUNK];
    __shared__ int h[NBKT];
    __shared__ int loff[NBKT];
    __shared__ int gb[NBKT];
    __shared__ int cur[NBKT];
    __shared__ int p[256];
    int t = threadIdx.x;
    int base = blockIdx.x * CHUNK;
    int cnt = NEDGE - base; if (cnt > CHUNK) cnt = CHUNK;

    h[t] = 0; h[t + 256] = 0; cur[t] = 0; cur[t + 256] = 0;
    __syncthreads();
    for (int j = t; j < cnt; j += 256)
        atomicAdd(&h[(unsigned)dst[base + j] / NPB], 1);
    __syncthreads();
    loff[2 * t] = h[2 * t]; loff[2 * t + 1] = h[2 * t + 1];
    __syncthreads();
    scan512(loff, p);
    if (h[t])       gb[t]       = atomicAdd(&gCur[t],       h[t]);
    if (h[t + 256]) gb[t + 256] = atomicAdd(&gCur[t + 256], h[t + 256]);
    loff[t]       -= h[t];
    loff[t + 256] -= h[t + 256];
    __syncthreads();
    for (int j = t; j < cnt; j += 256) {
        unsigned d = (unsigned)dst[base + j];
        unsigned b = d / NPB;
        int packed = (int)(((d - b * NPB) << 18) | (unsigned)src[base + j]);
        int pl = atomicAdd(&cur[b], 1);
        int slot = loff[b] + pl;
        sv[slot] = packed;
        gd[slot] = gb[b] + pl;
    }
    __syncthreads();
    for (int j = t; j < cnt; j += 256)
        E[gd[j]] = sv[j];
}

// ---- pass C: per-bucket CSR build + dinv/end ----
__global__ void k_csr(const int* __restrict__ E, const int* __restrict__ bStart,
                      int* __restrict__ csr, float* __restrict__ dinv,
                      int* __restrict__ endArr) {
    __shared__ int eL[CAP];
    __shared__ int csrL[CAP];
    __shared__ int cnt[NBKT];
    __shared__ int off[NBKT];
    __shared__ int cur[NBKT];
    __shared__ int p[256];
    int t = threadIdx.x;
    int b = blockIdx.x;
    int base = bStart[b];
    int n = bStart[b + 1] - base;
    int nodes = NTOKEN - b * NPB; if (nodes > NPB) nodes = NPB;

    cnt[t] = 0; cnt[t + 256] = 0;
    __syncthreads();
    bool fits = (n <= CAP);
    if (fits) {
        for (int j = t; j < n; j += 256) {
            int v = E[base + j];
            eL[j] = v;
            atomicAdd(&cnt[v >> 18], 1);
        }
    } else {
        for (int j = t; j < n; j += 256)
            atomicAdd(&cnt[E[base + j] >> 18], 1);
    }
    __syncthreads();
    off[2 * t] = cnt[2 * t]; off[2 * t + 1] = cnt[2 * t + 1];
    __syncthreads();
    scan512(off, p);
    for (int i = t; i < nodes; i += 256) {
        dinv[b * NPB + i]   = rsqrtf((float)(cnt[i] + 1));
        endArr[b * NPB + i] = base + off[i];
    }
    cur[t] = off[t] - cnt[t];
    cur[t + 256] = off[t + 256] - cnt[t + 256];
    __syncthreads();
    if (fits) {
        for (int j = t; j < n; j += 256) {
            int v = eL[j];
            int pos = atomicAdd(&cur[v >> 18], 1);
            csrL[pos] = v & 0x3FFFF;
        }
        __syncthreads();
        for (int j = t; j < n; j += 256)
            csr[base + j] = csrL[j];
    } else {
        for (int j = t; j < n; j += 256) {
            int v = E[base + j];
            int pos = atomicAdd(&cur[v >> 18], 1);
            csr[base + pos] = v & 0x3FFFF;
        }
    }
}

// ---- need2: wave per token, lane-parallel edge expansion, dedup -> compact list ----
__global__ void k_need2(const int* __restrict__ inp, const int* __restrict__ endArr,
                        const int* __restrict__ csr, int* __restrict__ flag,
                        int* __restrict__ nlist, int* __restrict__ ncnt) {
    int t = blockIdx.x * 4 + (threadIdx.x >> 6);
    if (t >= NBL) return;
    int lane = threadIdx.x & 63;
    int n = inp[t];
    int b = (n > 0) ? endArr[n - 1] : 0;
    int f = endArr[n];
    int deg = f - b;
    if (lane == 0) {
        if (atomicExch(&flag[n], 1) == 0) nlist[atomicAdd(ncnt, 1)] = n;
    }
    for (int e = lane; e < deg; e += 64) {
        int s = csr[b + e];
        if (atomicExch(&flag[s], 1) == 0) nlist[atomicAdd(ncnt, 1)] = s;
    }
}

// ---- layer 1 gather over compacted list, 4-way MLP ----
__global__ void k_gather1(const int* __restrict__ nlist, const int* __restrict__ ncnt,
                          const int* __restrict__ endArr, const int* __restrict__ csr,
                          const float* __restrict__ dinv, const float* __restrict__ emb,
                          float* __restrict__ P1) {
    int lane = threadIdx.x & 63;
    int wid = blockIdx.x * (blockDim.x >> 6) + (threadIdx.x >> 6);
    int nw  = gridDim.x * (blockDim.x >> 6);
    int ncount = *ncnt;
    for (int idx = wid; idx < ncount; idx += nw) {
        int i = nlist[idx];
        int b = (i > 0) ? endArr[i - 1] : 0;
        int f = endArr[i];
        int deg = f - b;
        float di = dinv[i];
        float a0 = di * emb[i * NINP + lane];
        float a1 = 0.f, a2 = 0.f, a3 = 0.f;
        for (int base = 0; base < deg; base += 64) {
            int m = deg - base; if (m > 64) m = 64;
            int myE = 0; float myW = 0.f;
            if (lane < m) { myE = csr[b + base + lane]; myW = dinv[myE]; }
            int e = 0;
            for (; e + 4 <= m; e += 4) {
                int   s0 = __shfl(myE, e),     s1 = __shfl(myE, e + 1);
                int   s2 = __shfl(myE, e + 2), s3 = __shfl(myE, e + 3);
                float w0 = __shfl(myW, e),     w1 = __shfl(myW, e + 1);
                float w2 = __shfl(myW, e + 2), w3 = __shfl(myW, e + 3);
                float v0 = emb[s0 * NINP + lane];
                float v1 = emb[s1 * NINP + lane];
                float v2 = emb[s2 * NINP + lane];
                float v3 = emb[s3 * NINP + lane];
                a0 += w0 * v0; a1 += w1 * v1; a2 += w2 * v2; a3 += w3 * v3;
            }
            for (; e < m; ++e) {
                int s0 = __shfl(myE, e); float w0 = __shfl(myW, e);
                a0 += w0 * emb[s0 * NINP + lane];
            }
        }
        P1[i * NINP + lane] = di * ((a0 + a1) + (a2 + a3));
    }
}

// ---- fold weights ----
__global__ void k_w12(const float* __restrict__ W1, const float* __restrict__ W2,
                      const float* __restrict__ b1, float* __restrict__ W12,
                      float* __restrict__ bb) {
    int id = blockIdx.x * blockDim.x + threadIdx.x;
    if (id < 64 * 64) {
        int i = id >> 6, j = id & 63;
        float acc = 0.f;
        for (int k = 0; k < 128; ++k) acc += W1[i * 128 + k] * W2[k * 64 + j];
        W12[id] = acc;
    } else if (id < 64 * 64 + 64) {
        int j = id - 64 * 64;
        float acc = 0.f;
        for (int k = 0; k < 128; ++k) acc += b1[k] * W2[k * 64 + j];
        bb[j] = acc;
    }
}

// ---- final: layer-2 gather (4-way MLP) + 64x64 GEMM + biases ----
__global__ void k_final(const int* __restrict__ inp, const int* __restrict__ endArr,
                        const int* __restrict__ csr, const float* __restrict__ dinv,
                        const float* __restrict__ P1, const float* __restrict__ W12,
                        const float* __restrict__ bb, const float* __restrict__ b2,
                        float* __restrict__ out) {
    int t = blockIdx.x * 4 + (threadIdx.x >> 6);
    if (t >= NBL) return;
    int lane = threadIdx.x & 63;
    int n = inp[t];
    float dn = dinv[n];
    int b = (n > 0) ? endArr[n - 1] : 0;
    int f = endArr[n];
    int deg = f - b;
    float a0 = dn * P1[n * NINP + lane];
    float a1 = 0.f, a2 = 0.f, a3 = 0.f;
    float sS = dn;
    for (int base = 0; base < deg; base += 64) {
        int m = deg - base; if (m > 64) m = 64;
        int myE = 0; float myW = 0.f;
        if (lane < m) { myE = csr[b + base + lane]; myW = dinv[myE]; }
        int e = 0;
        for (; e + 4 <= m; e += 4) {
            int   s0 = __shfl(myE, e),     s1 = __shfl(myE, e + 1);
            int   s2 = __shfl(myE, e + 2), s3 = __shfl(myE, e + 3);
            float w0 = __shfl(myW, e),     w1 = __shfl(myW, e + 1);
            float w2 = __shfl(myW, e + 2), w3 = __shfl(myW, e + 3);
            float v0 = P1[s0 * NINP + lane];
            float v1 = P1[s1 * NINP + lane];
            float v2 = P1[s2 * NINP + lane];
            float v3 = P1[s3 * NINP + lane];
            a0 += w0 * v0; a1 += w1 * v1; a2 += w2 * v2; a3 += w3 * v3;
            sS += w0 + w1 + w2 + w3;
        }
        for (; e < m; ++e) {
            int s0 = __shfl(myE, e); float w0 = __shfl(myW, e);
            a0 += w0 * P1[s0 * NINP + lane];
            sS += w0;
        }
    }
    float p2 = dn * ((a0 + a1) + (a2 + a3));
    float acc = b2[lane] + dn * sS * bb[lane];
#pragma unroll
    for (int k = 0; k < 64; ++k)
        acc += __shfl(p2, k) * W12[k * 64 + lane];
    out[t * 64 + lane] = acc;
}

extern "C" void kernel_launch(void* const* d_in, const int* in_sizes, int n_in,
                              void* d_out, int out_size, void* d_ws, size_t ws_size,
                              hipStream_t stream) {
    const int*   inp  = (const int*)d_in[0];
    const int*   eidx = (const int*)d_in[3];
    const int*   esrc = eidx;
    const int*   edst = eidx + NEDGE;
    const float* emb  = (const float*)d_in[4];
    const float* W1   = (const float*)d_in[5];
    const float* b1   = (const float*)d_in[6];
    const float* W2   = (const float*)d_in[7];
    const float* b2   = (const float*)d_in[8];
    float* out = (float*)d_out;

    char* ws = (char*)d_ws;
    int*   bCnt   = (int*)(ws + 0);          // 2,048
    int*   bStart = (int*)(ws + 4096);       // 2,052
    int*   gCur   = (int*)(ws + 8192);       // 2,048
    int*   ncnt   = (int*)(ws + 12288);      // 4
    float* dinv   = (float*)(ws + 16384);    // 800,000
    int*   endArr = (int*)(ws + 817152);     // 800,000
    int*   flag   = (int*)(ws + 1617408);    // 800,000
    int*   nlist  = (int*)(ws + 2417408);    // 800,000
    int*   E      = (int*)(ws + 3217408);    // 8,000,000
    int*   csr    = (int*)(ws + 11217408);   // 8,000,000
    float* W12    = (float*)(ws + 19217408); // 16,384
    float* bb     = (float*)(ws + 19233792); // 256
    float* P1     = (float*)(ws + 19234048); // 51,200,000 (end ~70.4 MB)

    const int B = 256;

    k_w12   <<<(64 * 64 + 64 + B - 1) / B, B, 0, stream>>>(W1, W2, b1, W12, bb);
    k_init  <<<(NTOKEN + B - 1) / B, B, 0, stream>>>(bCnt, flag, ncnt);
    k_hist  <<<1024, B, 0, stream>>>(edst, bCnt);
    k_scanB <<<1, NBKT, 0, stream>>>(bCnt, bStart, gCur);
    k_bucket<<<NCHUNK, B, 0, stream>>>(esrc, edst, gCur, E);
    k_csr   <<<NBKT, B, 0, stream>>>(E, bStart, csr, dinv, endArr);

    k_need2 <<<(NBL + 3) / 4, B, 0, stream>>>(inp, endArr, csr, flag, nlist, ncnt);
    k_gather1<<<2048, B, 0, stream>>>(nlist, ncnt, endArr, csr, dinv, emb, P1);

    k_final <<<(NBL + 3) / 4, B, 0, stream>>>(inp, endArr, csr, dinv, P1, W12, bb, b2, out);
}

// Round 5
// 155.538 us; speedup vs baseline: 2.6476x; 2.6476x over previous
//
#include <hip/hip_runtime.h>

#define NTOKEN 200000
#define NINP   64
#define NEDGE  2000000
#define NBL    12800
#define NBKT   512
#define NPB    391            // nodes per bucket
#define CHUNK  4096
#define NCHUNK ((NEDGE + CHUNK - 1) / CHUNK)   // 489
#define CAP    6144

// ---- inclusive scan of s[0..511] with 256 threads; p is 256-int temp ----
__device__ __forceinline__ void scan512(int* s, int* p) {
    int t = threadIdx.x;
    int a = s[2 * t], b = s[2 * t + 1];
    p[t] = a + b;
    __syncthreads();
    for (int d = 1; d < 256; d <<= 1) {
        int v = (t >= d) ? p[t - d] : 0;
        __syncthreads();
        p[t] += v;
        __syncthreads();
    }
    int incl = p[t];
    s[2 * t + 1] = incl;
    s[2 * t]     = incl - b;
    __syncthreads();
}

__global__ void k_init(int* __restrict__ bCnt, unsigned char* __restrict__ mark,
                       int* __restrict__ ncnt) {
    int i = blockIdx.x * blockDim.x + threadIdx.x;
    if (i < NBKT) bCnt[i] = 0;
    if (i < NTOKEN) mark[i] = 0;
    if (i == 0) *ncnt = 0;
}

// ---- pass A: bucket histogram, LDS pre-aggregated ----
__global__ void k_hist(const int* __restrict__ dst, int* __restrict__ bCnt) {
    __shared__ int h[NBKT];
    int t = threadIdx.x;
    h[t] = 0; h[t + 256] = 0;
    __syncthreads();
    for (int e = blockIdx.x * blockDim.x + t; e < NEDGE; e += gridDim.x * blockDim.x)
        atomicAdd(&h[(unsigned)dst[e] / NPB], 1);
    __syncthreads();
    if (h[t])       atomicAdd(&bCnt[t], h[t]);
    if (h[t + 256]) atomicAdd(&bCnt[t + 256], h[t + 256]);
}

// ---- pass S: scan bucket counts ----
__global__ void k_scanB(const int* __restrict__ bCnt, int* __restrict__ bStart,
                        int* __restrict__ gCur) {
    __shared__ int buf[NBKT];
    int t = threadIdx.x;
    int v = bCnt[t];
    buf[t] = v;
    __syncthreads();
    for (int d = 1; d < NBKT; d <<= 1) {
        int add = (t >= d) ? buf[t - d] : 0;
        __syncthreads();
        buf[t] += add;
        __syncthreads();
    }
    bStart[t + 1] = buf[t];
    gCur[t] = buf[t] - v;
    if (t == 0) bStart[0] = 0;
}

// ---- pass B: chunked bucket scatter with coalesced writes ----
__global__ void k_bucket(const int* __restrict__ src, const int* __restrict__ dst,
                         int* __restrict__ gCur, int* __restrict__ E) {
    __shared__ int sv[CHUNK];
    __shared__ int gd[CHUNK];
    __shared__ int h[NBKT];
    __shared__ int loff[NBKT];
    __shared__ int gb[NBKT];
    __shared__ int cur[NBKT];
    __shared__ int p[256];
    int t = threadIdx.x;
    int base = blockIdx.x * CHUNK;
    int cnt = NEDGE - base; if (cnt > CHUNK) cnt = CHUNK;

    h[t] = 0; h[t + 256] = 0; cur[t] = 0; cur[t + 256] = 0;
    __syncthreads();
    for (int j = t; j < cnt; j += 256)
        atomicAdd(&h[(unsigned)dst[base + j] / NPB], 1);
    __syncthreads();
    loff[2 * t] = h[2 * t]; loff[2 * t + 1] = h[2 * t + 1];
    __syncthreads();
    scan512(loff, p);
    if (h[t])       gb[t]       = atomicAdd(&gCur[t],       h[t]);
    if (h[t + 256]) gb[t + 256] = atomicAdd(&gCur[t + 256], h[t + 256]);
    loff[t]       -= h[t];
    loff[t + 256] -= h[t + 256];
    __syncthreads();
    for (int j = t; j < cnt; j += 256) {
        unsigned d = (unsigned)dst[base + j];
        unsigned b = d / NPB;
        int packed = (int)(((d - b * NPB) << 18) | (unsigned)src[base + j]);
        int pl = atomicAdd(&cur[b], 1);
        int slot = loff[b] + pl;
        sv[slot] = packed;
        gd[slot] = gb[b] + pl;
    }
    __syncthreads();
    for (int j = t; j < cnt; j += 256)
        E[gd[j]] = sv[j];
}

// ---- pass C: per-bucket CSR build + dinv/end ----
__global__ void k_csr(const int* __restrict__ E, const int* __restrict__ bStart,
                      int* __restrict__ csr, float* __restrict__ dinv,
                      int* __restrict__ endArr) {
    __shared__ int eL[CAP];
    __shared__ int csrL[CAP];
    __shared__ int cnt[NBKT];
    __shared__ int off[NBKT];
    __shared__ int cur[NBKT];
    __shared__ int p[256];
    int t = threadIdx.x;
    int b = blockIdx.x;
    int base = bStart[b];
    int n = bStart[b + 1] - base;
    int nodes = NTOKEN - b * NPB; if (nodes > NPB) nodes = NPB;

    cnt[t] = 0; cnt[t + 256] = 0;
    __syncthreads();
    bool fits = (n <= CAP);
    if (fits) {
        for (int j = t; j < n; j += 256) {
            int v = E[base + j];
            eL[j] = v;
            atomicAdd(&cnt[v >> 18], 1);
        }
    } else {
        for (int j = t; j < n; j += 256)
            atomicAdd(&cnt[E[base + j] >> 18], 1);
    }
    __syncthreads();
    off[2 * t] = cnt[2 * t]; off[2 * t + 1] = cnt[2 * t + 1];
    __syncthreads();
    scan512(off, p);
    for (int i = t; i < nodes; i += 256) {
        dinv[b * NPB + i]   = rsqrtf((float)(cnt[i] + 1));
        endArr[b * NPB + i] = base + off[i];
    }
    cur[t] = off[t] - cnt[t];
    cur[t + 256] = off[t + 256] - cnt[t + 256];
    __syncthreads();
    if (fits) {
        for (int j = t; j < n; j += 256) {
            int v = eL[j];
            int pos = atomicAdd(&cur[v >> 18], 1);
            csrL[pos] = v & 0x3FFFF;
        }
        __syncthreads();
        for (int j = t; j < n; j += 256)
            csr[base + j] = csrL[j];
    } else {
        for (int j = t; j < n; j += 256) {
            int v = E[base + j];
            int pos = atomicAdd(&cur[v >> 18], 1);
            csr[base + pos] = v & 0x3FFFF;
        }
    }
}

// ---- mark needed nodes: wave per token, plain byte stores (no atomics) ----
__global__ void k_mark2(const int* __restrict__ inp, const int* __restrict__ endArr,
                        const int* __restrict__ csr, unsigned char* __restrict__ mark) {
    int t = blockIdx.x * 4 + (threadIdx.x >> 6);
    if (t >= NBL) return;
    int lane = threadIdx.x & 63;
    int n = inp[t];
    int b = (n > 0) ? endArr[n - 1] : 0;
    int f = endArr[n];
    if (lane == 0) mark[n] = 1;
    for (int e = b + lane; e < f; e += 64) mark[csr[e]] = 1;
}

// ---- compact marked nodes -> nlist (one global atomic per block) ----
__global__ void k_compactL(const unsigned char* __restrict__ mark,
                           int* __restrict__ nlist, int* __restrict__ ncnt) {
    __shared__ int wbase[4];
    int t = threadIdx.x;
    int i = blockIdx.x * 256 + t;
    int m = (i < NTOKEN) ? (mark[i] ? 1 : 0) : 0;
    unsigned long long bal = __ballot(m);
    int w = t >> 6, lane = t & 63;
    int rank = __popcll(bal & ((1ull << lane) - 1ull));
    if (lane == 0) wbase[w] = __popcll(bal);
    __syncthreads();
    if (t == 0) {
        int s0 = wbase[0], s1 = wbase[1], s2 = wbase[2], s3 = wbase[3];
        int tot = s0 + s1 + s2 + s3;
        int base = tot ? atomicAdd(ncnt, tot) : 0;
        wbase[0] = base; wbase[1] = base + s0;
        wbase[2] = base + s0 + s1; wbase[3] = base + s0 + s1 + s2;
    }
    __syncthreads();
    if (m) nlist[wbase[w] + rank] = i;
}

// ---- layer 1 gather over compacted list, 4-way MLP ----
__global__ void k_gather1(const int* __restrict__ nlist, const int* __restrict__ ncnt,
                          const int* __restrict__ endArr, const int* __restrict__ csr,
                          const float* __restrict__ dinv, const float* __restrict__ emb,
                          float* __restrict__ P1) {
    int lane = threadIdx.x & 63;
    int wid = blockIdx.x * (blockDim.x >> 6) + (threadIdx.x >> 6);
    int nw  = gridDim.x * (blockDim.x >> 6);
    int ncount = *ncnt;
    for (int idx = wid; idx < ncount; idx += nw) {
        int i = nlist[idx];
        int b = (i > 0) ? endArr[i - 1] : 0;
        int f = endArr[i];
        int deg = f - b;
        float di = dinv[i];
        float a0 = di * emb[i * NINP + lane];
        float a1 = 0.f, a2 = 0.f, a3 = 0.f;
        for (int base = 0; base < deg; base += 64) {
            int m = deg - base; if (m > 64) m = 64;
            int myE = 0; float myW = 0.f;
            if (lane < m) { myE = csr[b + base + lane]; myW = dinv[myE]; }
            int e = 0;
            for (; e + 4 <= m; e += 4) {
                int   s0 = __shfl(myE, e),     s1 = __shfl(myE, e + 1);
                int   s2 = __shfl(myE, e + 2), s3 = __shfl(myE, e + 3);
                float w0 = __shfl(myW, e),     w1 = __shfl(myW, e + 1);
                float w2 = __shfl(myW, e + 2), w3 = __shfl(myW, e + 3);
                float v0 = emb[s0 * NINP + lane];
                float v1 = emb[s1 * NINP + lane];
                float v2 = emb[s2 * NINP + lane];
                float v3 = emb[s3 * NINP + lane];
                a0 += w0 * v0; a1 += w1 * v1; a2 += w2 * v2; a3 += w3 * v3;
            }
            for (; e < m; ++e) {
                int s0 = __shfl(myE, e); float w0 = __shfl(myW, e);
                a0 += w0 * emb[s0 * NINP + lane];
            }
        }
        P1[i * NINP + lane] = di * ((a0 + a1) + (a2 + a3));
    }
}

// ---- fold weights ----
__global__ void k_w12(const float* __restrict__ W1, const float* __restrict__ W2,
                      const float* __restrict__ b1, float* __restrict__ W12,
                      float* __restrict__ bb) {
    int id = blockIdx.x * blockDim.x + threadIdx.x;
    if (id < 64 * 64) {
        int i = id >> 6, j = id & 63;
        float acc = 0.f;
        for (int k = 0; k < 128; ++k) acc += W1[i * 128 + k] * W2[k * 64 + j];
        W12[id] = acc;
    } else if (id < 64 * 64 + 64) {
        int j = id - 64 * 64;
        float acc = 0.f;
        for (int k = 0; k < 128; ++k) acc += b1[k] * W2[k * 64 + j];
        bb[j] = acc;
    }
}

// ---- final: layer-2 gather (4-way MLP) + 64x64 GEMM + biases ----
__global__ void k_final(const int* __restrict__ inp, const int* __restrict__ endArr,
                        const int* __restrict__ csr, const float* __restrict__ dinv,
                        const float* __restrict__ P1, const float* __restrict__ W12,
                        const float* __restrict__ bb, const float* __restrict__ b2,
                        float* __restrict__ out) {
    int t = blockIdx.x * 4 + (threadIdx.x >> 6);
    if (t >= NBL) return;
    int lane = threadIdx.x & 63;
    int n = inp[t];
    float dn = dinv[n];
    int b = (n > 0) ? endArr[n - 1] : 0;
    int f = endArr[n];
    int deg = f - b;
    float a0 = dn * P1[n * NINP + lane];
    float a1 = 0.f, a2 = 0.f, a3 = 0.f;
    float sS = dn;
    for (int base = 0; base < deg; base += 64) {
        int m = deg - base; if (m > 64) m = 64;
        int myE = 0; float myW = 0.f;
        if (lane < m) { myE = csr[b + base + lane]; myW = dinv[myE]; }
        int e = 0;
        for (; e + 4 <= m; e += 4) {
            int   s0 = __shfl(myE, e),     s1 = __shfl(myE, e + 1);
            int   s2 = __shfl(myE, e + 2), s3 = __shfl(myE, e + 3);
            float w0 = __shfl(myW, e),     w1 = __shfl(myW, e + 1);
            float w2 = __shfl(myW, e + 2), w3 = __shfl(myW, e + 3);
            float v0 = P1[s0 * NINP + lane];
            float v1 = P1[s1 * NINP + lane];
            float v2 = P1[s2 * NINP + lane];
            float v3 = P1[s3 * NINP + lane];
            a0 += w0 * v0; a1 += w1 * v1; a2 += w2 * v2; a3 += w3 * v3;
            sS += w0 + w1 + w2 + w3;
        }
        for (; e < m; ++e) {
            int s0 = __shfl(myE, e); float w0 = __shfl(myW, e);
            a0 += w0 * P1[s0 * NINP + lane];
            sS += w0;
        }
    }
    float p2 = dn * ((a0 + a1) + (a2 + a3));
    float acc = b2[lane] + dn * sS * bb[lane];
#pragma unroll
    for (int k = 0; k < 64; ++k)
        acc += __shfl(p2, k) * W12[k * 64 + lane];
    out[t * 64 + lane] = acc;
}

extern "C" void kernel_launch(void* const* d_in, const int* in_sizes, int n_in,
                              void* d_out, int out_size, void* d_ws, size_t ws_size,
                              hipStream_t stream) {
    const int*   inp  = (const int*)d_in[0];
    const int*   eidx = (const int*)d_in[3];
    const int*   esrc = eidx;
    const int*   edst = eidx + NEDGE;
    const float* emb  = (const float*)d_in[4];
    const float* W1   = (const float*)d_in[5];
    const float* b1   = (const float*)d_in[6];
    const float* W2   = (const float*)d_in[7];
    const float* b2   = (const float*)d_in[8];
    float* out = (float*)d_out;

    char* ws = (char*)d_ws;
    int*           bCnt   = (int*)(ws + 0);          // 2,048
    int*           bStart = (int*)(ws + 4096);       // 2,052
    int*           gCur   = (int*)(ws + 8192);       // 2,048
    int*           ncnt   = (int*)(ws + 12288);      // 4
    float*         dinv   = (float*)(ws + 16384);    // 800,000
    int*           endArr = (int*)(ws + 817152);     // 800,000
    unsigned char* mark   = (unsigned char*)(ws + 1617408); // 200,000
    int*           nlist  = (int*)(ws + 1817600);    // 800,000
    int*           E      = (int*)(ws + 2617600);    // 8,000,000
    int*           csr    = (int*)(ws + 10617600);   // 8,000,000
    float*         W12    = (float*)(ws + 18617600); // 16,384
    float*         bb     = (float*)(ws + 18633984); // 256
    float*         P1     = (float*)(ws + 18634240); // 51,200,000 (end ~69.8 MB)

    const int B = 256;

    k_w12   <<<(64 * 64 + 64 + B - 1) / B, B, 0, stream>>>(W1, W2, b1, W12, bb);
    k_init  <<<(NTOKEN + B - 1) / B, B, 0, stream>>>(bCnt, mark, ncnt);
    k_hist  <<<1024, B, 0, stream>>>(edst, bCnt);
    k_scanB <<<1, NBKT, 0, stream>>>(bCnt, bStart, gCur);
    k_bucket<<<NCHUNK, B, 0, stream>>>(esrc, edst, gCur, E);
    k_csr   <<<NBKT, B, 0, stream>>>(E, bStart, csr, dinv, endArr);

    k_mark2   <<<(NBL + 3) / 4, B, 0, stream>>>(inp, endArr, csr, mark);
    k_compactL<<<(NTOKEN + B - 1) / B, B, 0, stream>>>(mark, nlist, ncnt);
    k_gather1 <<<2048, B, 0, stream>>>(nlist, ncnt, endArr, csr, dinv, emb, P1);

    k_final <<<(NBL + 3) / 4, B, 0, stream>>>(inp, endArr, csr, dinv, P1, W12, bb, b2, out);
}

// Round 6
// 154.629 us; speedup vs baseline: 2.6632x; 1.0059x over previous
//
#include <hip/hip_runtime.h>

#define NTOKEN 200000
#define NINP   64
#define NEDGE  2000000
#define NBL    12800
#define NBKT   512
#define NPB    391            // nodes per bucket
#define CHUNK  4096
#define NCHUNK ((NEDGE + CHUNK - 1) / CHUNK)   // 489
#define CAP    6144

// ---- inclusive scan of s[0..511] with 256 threads; p is 256-int temp ----
__device__ __forceinline__ void scan512(int* s, int* p) {
    int t = threadIdx.x;
    int a = s[2 * t], b = s[2 * t + 1];
    p[t] = a + b;
    __syncthreads();
    for (int d = 1; d < 256; d <<= 1) {
        int v = (t >= d) ? p[t - d] : 0;
        __syncthreads();
        p[t] += v;
        __syncthreads();
    }
    int incl = p[t];
    s[2 * t + 1] = incl;
    s[2 * t]     = incl - b;
    __syncthreads();
}

__global__ void k_init(int* __restrict__ bCnt, unsigned char* __restrict__ mark,
                       int* __restrict__ ncnt) {
    int i = blockIdx.x * blockDim.x + threadIdx.x;
    if (i < NBKT) bCnt[i] = 0;
    if (i < NTOKEN) mark[i] = 0;
    if (i == 0) *ncnt = 0;
}

// ---- pass A: bucket histogram, LDS pre-aggregated ----
__global__ void k_hist(const int* __restrict__ dst, int* __restrict__ bCnt) {
    __shared__ int h[NBKT];
    int t = threadIdx.x;
    h[t] = 0; h[t + 256] = 0;
    __syncthreads();
    for (int e = blockIdx.x * blockDim.x + t; e < NEDGE; e += gridDim.x * blockDim.x)
        atomicAdd(&h[(unsigned)dst[e] / NPB], 1);
    __syncthreads();
    if (h[t])       atomicAdd(&bCnt[t], h[t]);
    if (h[t + 256]) atomicAdd(&bCnt[t + 256], h[t + 256]);
}

// ---- pass S: scan bucket counts ----
__global__ void k_scanB(const int* __restrict__ bCnt, int* __restrict__ bStart,
                        int* __restrict__ gCur) {
    __shared__ int buf[NBKT];
    int t = threadIdx.x;
    int v = bCnt[t];
    buf[t] = v;
    __syncthreads();
    for (int d = 1; d < NBKT; d <<= 1) {
        int add = (t >= d) ? buf[t - d] : 0;
        __syncthreads();
        buf[t] += add;
        __syncthreads();
    }
    bStart[t + 1] = buf[t];
    gCur[t] = buf[t] - v;
    if (t == 0) bStart[0] = 0;
}

// ---- pass B: chunked bucket scatter with coalesced writes ----
__global__ void k_bucket(const int* __restrict__ src, const int* __restrict__ dst,
                         int* __restrict__ gCur, int* __restrict__ E) {
    __shared__ int sv[CHUNK];
    __shared__ int gd[CHUNK];
    __shared__ int h[NBKT];
    __shared__ int loff[NBKT];
    __shared__ int gb[NBKT];
    __shared__ int cur[NBKT];
    __shared__ int p[256];
    int t = threadIdx.x;
    int base = blockIdx.x * CHUNK;
    int cnt = NEDGE - base; if (cnt > CHUNK) cnt = CHUNK;

    h[t] = 0; h[t + 256] = 0; cur[t] = 0; cur[t + 256] = 0;
    __syncthreads();
    for (int j = t; j < cnt; j += 256)
        atomicAdd(&h[(unsigned)dst[base + j] / NPB], 1);
    __syncthreads();
    loff[2 * t] = h[2 * t]; loff[2 * t + 1] = h[2 * t + 1];
    __syncthreads();
    scan512(loff, p);
    if (h[t])       gb[t]       = atomicAdd(&gCur[t],       h[t]);
    if (h[t + 256]) gb[t + 256] = atomicAdd(&gCur[t + 256], h[t + 256]);
    loff[t]       -= h[t];
    loff[t + 256] -= h[t + 256];
    __syncthreads();
    for (int j = t; j < cnt; j += 256) {
        unsigned d = (unsigned)dst[base + j];
        unsigned b = d / NPB;
        int packed = (int)(((d - b * NPB) << 18) | (unsigned)src[base + j]);
        int pl = atomicAdd(&cur[b], 1);
        int slot = loff[b] + pl;
        sv[slot] = packed;
        gd[slot] = gb[b] + pl;
    }
    __syncthreads();
    for (int j = t; j < cnt; j += 256)
        E[gd[j]] = sv[j];
}

// ---- pass C: per-bucket CSR build + dinv/end ----
__global__ void k_csr(const int* __restrict__ E, const int* __restrict__ bStart,
                      int* __restrict__ csr, float* __restrict__ dinv,
                      int* __restrict__ endArr) {
    __shared__ int eL[CAP];
    __shared__ int csrL[CAP];
    __shared__ int cnt[NBKT];
    __shared__ int off[NBKT];
    __shared__ int cur[NBKT];
    __shared__ int p[256];
    int t = threadIdx.x;
    int b = blockIdx.x;
    int base = bStart[b];
    int n = bStart[b + 1] - base;
    int nodes = NTOKEN - b * NPB; if (nodes > NPB) nodes = NPB;

    cnt[t] = 0; cnt[t + 256] = 0;
    __syncthreads();
    bool fits = (n <= CAP);
    if (fits) {
        for (int j = t; j < n; j += 256) {
            int v = E[base + j];
            eL[j] = v;
            atomicAdd(&cnt[v >> 18], 1);
        }
    } else {
        for (int j = t; j < n; j += 256)
            atomicAdd(&cnt[E[base + j] >> 18], 1);
    }
    __syncthreads();
    off[2 * t] = cnt[2 * t]; off[2 * t + 1] = cnt[2 * t + 1];
    __syncthreads();
    scan512(off, p);
    for (int i = t; i < nodes; i += 256) {
        dinv[b * NPB + i]   = rsqrtf((float)(cnt[i] + 1));
        endArr[b * NPB + i] = base + off[i];
    }
    cur[t] = off[t] - cnt[t];
    cur[t + 256] = off[t + 256] - cnt[t + 256];
    __syncthreads();
    if (fits) {
        for (int j = t; j < n; j += 256) {
            int v = eL[j];
            int pos = atomicAdd(&cur[v >> 18], 1);
            csrL[pos] = v & 0x3FFFF;
        }
        __syncthreads();
        for (int j = t; j < n; j += 256)
            csr[base + j] = csrL[j];
    } else {
        for (int j = t; j < n; j += 256) {
            int v = E[base + j];
            int pos = atomicAdd(&cur[v >> 18], 1);
            csr[base + pos] = v & 0x3FFFF;
        }
    }
}

// ---- mark needed nodes: wave per token, plain byte stores (no atomics) ----
__global__ void k_mark2(const int* __restrict__ inp, const int* __restrict__ endArr,
                        const int* __restrict__ csr, unsigned char* __restrict__ mark) {
    int t = blockIdx.x * 4 + (threadIdx.x >> 6);
    if (t >= NBL) return;
    int lane = threadIdx.x & 63;
    int n = inp[t];
    int b = (n > 0) ? endArr[n - 1] : 0;
    int f = endArr[n];
    if (lane == 0) mark[n] = 1;
    for (int e = b + lane; e < f; e += 64) mark[csr[e]] = 1;
}

// ---- compact marked nodes -> nlist (one global atomic per block) ----
__global__ void k_compactL(const unsigned char* __restrict__ mark,
                           int* __restrict__ nlist, int* __restrict__ ncnt) {
    __shared__ int wbase[4];
    int t = threadIdx.x;
    int i = blockIdx.x * 256 + t;
    int m = (i < NTOKEN) ? (mark[i] ? 1 : 0) : 0;
    unsigned long long bal = __ballot(m);
    int w = t >> 6, lane = t & 63;
    int rank = __popcll(bal & ((1ull << lane) - 1ull));
    if (lane == 0) wbase[w] = __popcll(bal);
    __syncthreads();
    if (t == 0) {
        int s0 = wbase[0], s1 = wbase[1], s2 = wbase[2], s3 = wbase[3];
        int tot = s0 + s1 + s2 + s3;
        int base = tot ? atomicAdd(ncnt, tot) : 0;
        wbase[0] = base; wbase[1] = base + s0;
        wbase[2] = base + s0 + s1; wbase[3] = base + s0 + s1 + s2;
    }
    __syncthreads();
    if (m) nlist[wbase[w] + rank] = i;
}

// ---- 8-wide edge-batch accumulator: 8 independent loads in flight ----
#define GATHER8(TAB)                                                            \
    for (int base = 0; base < deg; base += 64) {                                \
        int m = deg - base; if (m > 64) m = 64;                                 \
        int myE = 0; float myW = 0.f;                                           \
        if (lane < m) { myE = csr[b + base + lane]; myW = dinv[myE]; }          \
        int e = 0;                                                              \
        for (; e + 8 <= m; e += 8) {                                            \
            int   s0 = __shfl(myE, e),     s1 = __shfl(myE, e + 1);             \
            int   s2 = __shfl(myE, e + 2), s3 = __shfl(myE, e + 3);             \
            int   s4 = __shfl(myE, e + 4), s5 = __shfl(myE, e + 5);             \
            int   s6 = __shfl(myE, e + 6), s7 = __shfl(myE, e + 7);             \
            float w0 = __shfl(myW, e),     w1 = __shfl(myW, e + 1);             \
            float w2 = __shfl(myW, e + 2), w3 = __shfl(myW, e + 3);             \
            float w4 = __shfl(myW, e + 4), w5 = __shfl(myW, e + 5);             \
            float w6 = __shfl(myW, e + 6), w7 = __shfl(myW, e + 7);             \
            float v0 = TAB[s0 * NINP + lane], v1 = TAB[s1 * NINP + lane];       \
            float v2 = TAB[s2 * NINP + lane], v3 = TAB[s3 * NINP + lane];       \
            float v4 = TAB[s4 * NINP + lane], v5 = TAB[s5 * NINP + lane];       \
            float v6 = TAB[s6 * NINP + lane], v7 = TAB[s7 * NINP + lane];       \
            a0 += w0 * v0; a1 += w1 * v1; a2 += w2 * v2; a3 += w3 * v3;         \
            a4 += w4 * v4; a5 += w5 * v5; a6 += w6 * v6; a7 += w7 * v7;         \
            sS += ((w0 + w1) + (w2 + w3)) + ((w4 + w5) + (w6 + w7));            \
        }                                                                       \
        for (; e + 4 <= m; e += 4) {                                            \
            int   s0 = __shfl(myE, e),     s1 = __shfl(myE, e + 1);             \
            int   s2 = __shfl(myE, e + 2), s3 = __shfl(myE, e + 3);             \
            float w0 = __shfl(myW, e),     w1 = __shfl(myW, e + 1);             \
            float w2 = __shfl(myW, e + 2), w3 = __shfl(myW, e + 3);             \
            float v0 = TAB[s0 * NINP + lane], v1 = TAB[s1 * NINP + lane];       \
            float v2 = TAB[s2 * NINP + lane], v3 = TAB[s3 * NINP + lane];       \
            a0 += w0 * v0; a1 += w1 * v1; a2 += w2 * v2; a3 += w3 * v3;         \
            sS += (w0 + w1) + (w2 + w3);                                        \
        }                                                                       \
        for (; e < m; ++e) {                                                    \
            int s0 = __shfl(myE, e); float w0 = __shfl(myW, e);                 \
            a0 += w0 * TAB[s0 * NINP + lane];                                   \
            sS += w0;                                                           \
        }                                                                       \
    }

// ---- layer 1 gather over compacted list, 8-way MLP ----
__global__ void k_gather1(const int* __restrict__ nlist, const int* __restrict__ ncnt,
                          const int* __restrict__ endArr, const int* __restrict__ csr,
                          const float* __restrict__ dinv, const float* __restrict__ emb,
                          float* __restrict__ P1) {
    int lane = threadIdx.x & 63;
    int wid = blockIdx.x * (blockDim.x >> 6) + (threadIdx.x >> 6);
    int nw  = gridDim.x * (blockDim.x >> 6);
    int ncount = *ncnt;
    for (int idx = wid; idx < ncount; idx += nw) {
        int i = nlist[idx];
        int b = (i > 0) ? endArr[i - 1] : 0;
        int deg = endArr[i] - b;
        float di = dinv[i];
        float a0 = di * emb[i * NINP + lane];
        float a1 = 0.f, a2 = 0.f, a3 = 0.f, a4 = 0.f, a5 = 0.f, a6 = 0.f, a7 = 0.f;
        float sS = 0.f;   // unused here
        GATHER8(emb)
        (void)sS;
        P1[i * NINP + lane] = di * (((a0 + a1) + (a2 + a3)) + ((a4 + a5) + (a6 + a7)));
    }
}

// ---- fold weights ----
__global__ void k_w12(const float* __restrict__ W1, const float* __restrict__ W2,
                      const float* __restrict__ b1, float* __restrict__ W12,
                      float* __restrict__ bb) {
    int id = blockIdx.x * blockDim.x + threadIdx.x;
    if (id < 64 * 64) {
        int i = id >> 6, j = id & 63;
        float acc = 0.f;
        for (int k = 0; k < 128; ++k) acc += W1[i * 128 + k] * W2[k * 64 + j];
        W12[id] = acc;
    } else if (id < 64 * 64 + 64) {
        int j = id - 64 * 64;
        float acc = 0.f;
        for (int k = 0; k < 128; ++k) acc += b1[k] * W2[k * 64 + j];
        bb[j] = acc;
    }
}

// ---- final: layer-2 gather (8-way MLP) + 64x64 GEMM + biases ----
__global__ void k_final(const int* __restrict__ inp, const int* __restrict__ endArr,
                        const int* __restrict__ csr, const float* __restrict__ dinv,
                        const float* __restrict__ P1, const float* __restrict__ W12,
                        const float* __restrict__ bb, const float* __restrict__ b2,
                        float* __restrict__ out) {
    int t = blockIdx.x * 4 + (threadIdx.x >> 6);
    if (t >= NBL) return;
    int lane = threadIdx.x & 63;
    int n = inp[t];
    float dn = dinv[n];
    int b = (n > 0) ? endArr[n - 1] : 0;
    int deg = endArr[n] - b;
    float a0 = dn * P1[n * NINP + lane];
    float a1 = 0.f, a2 = 0.f, a3 = 0.f, a4 = 0.f, a5 = 0.f, a6 = 0.f, a7 = 0.f;
    float sS = dn;
    GATHER8(P1)
    float p2 = dn * (((a0 + a1) + (a2 + a3)) + ((a4 + a5) + (a6 + a7)));
    float acc = b2[lane] + dn * sS * bb[lane];
#pragma unroll
    for (int k = 0; k < 64; ++k)
        acc += __shfl(p2, k) * W12[k * 64 + lane];
    out[t * 64 + lane] = acc;
}

extern "C" void kernel_launch(void* const* d_in, const int* in_sizes, int n_in,
                              void* d_out, int out_size, void* d_ws, size_t ws_size,
                              hipStream_t stream) {
    const int*   inp  = (const int*)d_in[0];
    const int*   eidx = (const int*)d_in[3];
    const int*   esrc = eidx;
    const int*   edst = eidx + NEDGE;
    const float* emb  = (const float*)d_in[4];
    const float* W1   = (const float*)d_in[5];
    const float* b1   = (const float*)d_in[6];
    const float* W2   = (const float*)d_in[7];
    const float* b2   = (const float*)d_in[8];
    float* out = (float*)d_out;

    char* ws = (char*)d_ws;
    int*           bCnt   = (int*)(ws + 0);          // 2,048
    int*           bStart = (int*)(ws + 4096);       // 2,052
    int*           gCur   = (int*)(ws + 8192);       // 2,048
    int*           ncnt   = (int*)(ws + 12288);      // 4
    float*         dinv   = (float*)(ws + 16384);    // 800,000
    int*           endArr = (int*)(ws + 817152);     // 800,000
    unsigned char* mark   = (unsigned char*)(ws + 1617408); // 200,000
    int*           nlist  = (int*)(ws + 1817600);    // 800,000
    int*           E      = (int*)(ws + 2617600);    // 8,000,000
    int*           csr    = (int*)(ws + 10617600);   // 8,000,000
    float*         W12    = (float*)(ws + 18617600); // 16,384
    float*         bb     = (float*)(ws + 18633984); // 256
    float*         P1     = (float*)(ws + 18634240); // 51,200,000 (end ~69.8 MB)

    const int B = 256;

    k_w12   <<<(64 * 64 + 64 + B - 1) / B, B, 0, stream>>>(W1, W2, b1, W12, bb);
    k_init  <<<(NTOKEN + B - 1) / B, B, 0, stream>>>(bCnt, mark, ncnt);
    k_hist  <<<1024, B, 0, stream>>>(edst, bCnt);
    k_scanB <<<1, NBKT, 0, stream>>>(bCnt, bStart, gCur);
    k_bucket<<<NCHUNK, B, 0, stream>>>(esrc, edst, gCur, E);
    k_csr   <<<NBKT, B, 0, stream>>>(E, bStart, csr, dinv, endArr);

    k_mark2   <<<(NBL + 3) / 4, B, 0, stream>>>(inp, endArr, csr, mark);
    k_compactL<<<(NTOKEN + B - 1) / B, B, 0, stream>>>(mark, nlist, ncnt);
    k_gather1 <<<2048, B, 0, stream>>>(nlist, ncnt, endArr, csr, dinv, emb, P1);

    k_final <<<(NBL + 3) / 4, B, 0, stream>>>(inp, endArr, csr, dinv, P1, W12, bb, b2, out);
}